// Round 17
// baseline (710.443 us; speedup 1.0000x reference)
//
#include <hip/hip_runtime.h>
#include <hip/hip_fp16.h>

#define NA 100000
#define NB 200000
#define MAXNB 6
#define AF 133
#define BF 147
#define H 300
#define HP 320     // padded fp16 row width for msg/amsg (640B)
#define AFP 160    // padded fp16 row width for f_bonds/f_atoms
#define NP 320     // weight N padding = BN
#define KP_C 480   // uniform K padding: [W_i(160); W_h(320)] / [atoms(160); amsg(320)]
#define BM 128
#define BN 320
#define BK 32
#define NTH 512
#define LDK 40     // LDS row stride (32 + 8 pad)

typedef _Float16 f16;
typedef __attribute__((ext_vector_type(8))) _Float16 f16x8;
typedef __attribute__((ext_vector_type(4))) float f32x4;

// ---- fp32 [M][Ks] -> fp16 [M][160] zero-padded ----------------------------
__global__ void conv_pad_f16(const float* __restrict__ src, f16* __restrict__ dst,
                             int M, int Ks) {
  int idx = blockIdx.x * blockDim.x + threadIdx.x;
  if (idx >= M * (AFP / 8)) return;
  int r = idx / (AFP / 8);
  int c = (idx - r * (AFP / 8)) * 8;
  f16x8 o;
#pragma unroll
  for (int j = 0; j < 8; ++j) {
    int k = c + j;
    o[j] = (k < Ks) ? (f16)src[(size_t)r * Ks + k] : (f16)0.0f;
  }
  *(f16x8*)&dst[(size_t)r * AFP + c] = o;
}

// ---- stacked [W_i; W_h] -> [n][k] fp16, stride KP_C ------------------------
__global__ void prep_w1(const float* __restrict__ Wi, const float* __restrict__ Wh,
                        f16* __restrict__ dst) {
  int idx = blockIdx.x * blockDim.x + threadIdx.x;
  if (idx >= NP * KP_C) return;
  int n = idx / KP_C, k = idx - n * KP_C;
  float v = 0.0f;
  if (n < H) {
    if (k < BF) v = Wi[(size_t)k * H + n];
    else if (k >= AFP && k < AFP + H) v = Wh[(size_t)(k - AFP) * H + n];
  }
  dst[idx] = (f16)v;
}

// ---- W_o remapped for [f_atoms(133->160 pad), amsg(300->320 pad)] ----------
__global__ void prep_wo(const float* __restrict__ src, f16* __restrict__ dst) {
  int idx = blockIdx.x * blockDim.x + threadIdx.x;
  if (idx >= NP * KP_C) return;
  int n = idx / KP_C, k = idx - n * KP_C;
  int ks = -1;
  if (k < AF) ks = k;
  else if (k >= AFP && k < AFP + H) ks = AF + (k - AFP);
  float v = (n < H && ks >= 0) ? src[(size_t)ks * H + n] : 0.0f;
  dst[idx] = (f16)v;
}

// ---- a_msg[a][:] = sum_t msg[a2b[a][t]][:] --------------------------------
__global__ void gather_sum_kernel(const f16* __restrict__ msg,
                                  const int* __restrict__ a2b,
                                  f16* __restrict__ amsg) {
  int idx = blockIdx.x * blockDim.x + threadIdx.x;
  if (idx >= NA * (HP / 8)) return;
  int a = idx / (HP / 8);
  int c = (idx - a * (HP / 8)) * 8;
  const int* nbr = &a2b[(size_t)a * MAXNB];
  float acc[8] = {0.f, 0.f, 0.f, 0.f, 0.f, 0.f, 0.f, 0.f};
#pragma unroll
  for (int t = 0; t < MAXNB; ++t) {
    int r = nbr[t];
    f16x8 v = *(const f16x8*)&msg[(size_t)r * HP + c];
#pragma unroll
    for (int j = 0; j < 8; ++j) acc[j] += (float)v[j];
  }
  f16x8 o;
#pragma unroll
  for (int j = 0; j < 8; ++j) o[j] = (f16)acc[j];
  *(f16x8*)&amsg[(size_t)a * HP + c] = o;
}

// ---- unified GEMM: 128x320 tile, 8 waves (2x4), BK=32, dbuf LDS -----------
// ONE barrier per k-step. BOTH A and B staging are 2-deep: two alternating
// register sets each, issued at the top of the iteration (two compute-phases
// before consumption), so HBM-random A latency AND L2 B latency are covered.
// MODE 0: msg = relu(fb16 @ W_i)                                (K=160)
// MODE 1: msg' = relu([fb16[m], amsg[b2a]-msg[b2revb]] @ [W_i;W_h])  (K=480)
// MODE 2: out = relu([fa16, sum_t msg[a2b[m][t]]] @ W_o + b_o)  (K=480, fused gather)
template <int MODE>
__global__ __launch_bounds__(NTH)
void gemm_kernel(const f16* __restrict__ Afp,    // fb16 (MODE 0/1) / fa16 (MODE 2)
                 const f16* __restrict__ amsg,   // MODE1 only: gathered per-atom sums
                 const f16* __restrict__ msg_in, // MODE1: prev msg; MODE2: final msg
                 const int* __restrict__ b2a,
                 const int* __restrict__ b2revb,
                 const int* __restrict__ a2b,    // MODE2 only
                 const f16* __restrict__ Wp,     // [NP][KP_C]
                 const float* __restrict__ b_o,
                 f16* __restrict__ out_msg,
                 float* __restrict__ out_f32) {
  constexpr int KSTEPS = (MODE == 0) ? 5 : 15;
  constexpr int ASTEPS = 5;                // k-steps sourced from Afp
  constexpr int M = (MODE == 2) ? NA : NB;

  __shared__ f16 As[2][BM][LDK];
  __shared__ f16 Bs[2][BN][LDK];

  const int mb = blockIdx.x;
  const int tid = threadIdx.x;
  const int lane = tid & 63, wid = tid >> 6;
  const int wr = wid >> 2, wc = wid & 3;   // 2 x 4 wave grid

  f32x4 acc[4][5] = {};

  // A staging: 512 8-elem chunks == NTH; thread -> (tid>>2, (tid&3)*8)
  const int arow = tid >> 2;
  const int ac = (tid & 3) * 8;
  const int m_g = mb * BM + arow;
  const int mrow = (m_g < M) ? m_g : 0;  // clamp: OOB rows masked in epilogue

  // B staging: 1280 chunks over 512 threads (3rd chunk partial, tid<256)
  const int bidx2 = tid + 2 * NTH;
  const int br0 = tid >> 2,            bc0 = (tid & 3) * 8;
  const int br1 = (tid + NTH) >> 2,    bc1 = ((tid + NTH) & 3) * 8;
  const int br2 = bidx2 >> 2,          bc2 = (bidx2 & 3) * 8;
  const bool b2ok = bidx2 < BN * 4;

  int ra = 0, rb = 0;
  int n0 = 0, n1 = 0, n2 = 0, n3 = 0, n4 = 0, n5 = 0;
  if constexpr (MODE == 1) { ra = b2a[mrow]; rb = b2revb[mrow]; }
  if constexpr (MODE == 2) {
    const int* p = &a2b[(size_t)mrow * MAXNB];
    n0 = p[0]; n1 = p[1]; n2 = p[2]; n3 = p[3]; n4 = p[4]; n5 = p[5];
  }

  // two alternating staging sets for A AND B (static names, rule #20)
  f16x8 axA, ayA, avA[6];
  f16x8 axB, ayB, avB[6];
  f16x8 pwA0, pwA1, pwA2;
  f16x8 pwB0, pwB1, pwB2;

  auto issueA = [&](int ks, f16x8& ax, f16x8& ay, f16x8 (&av)[6]) {
    const int kb = ks * BK + ac;
    if constexpr (MODE == 0) {
      ax = *(const f16x8*)&Afp[(size_t)mrow * AFP + kb];
    } else if constexpr (MODE == 1) {
      if (ks < ASTEPS) {
        ax = *(const f16x8*)&Afp[(size_t)mrow * AFP + kb];
      } else {
        const int kk = kb - AFP;
        ax = *(const f16x8*)&amsg[(size_t)ra * HP + kk];
        ay = *(const f16x8*)&msg_in[(size_t)rb * HP + kk];
      }
    } else {
      if (ks < ASTEPS) {
        ax = *(const f16x8*)&Afp[(size_t)mrow * AFP + kb];
      } else {
        const int kk = kb - AFP;
        av[0] = *(const f16x8*)&msg_in[(size_t)n0 * HP + kk];
        av[1] = *(const f16x8*)&msg_in[(size_t)n1 * HP + kk];
        av[2] = *(const f16x8*)&msg_in[(size_t)n2 * HP + kk];
        av[3] = *(const f16x8*)&msg_in[(size_t)n3 * HP + kk];
        av[4] = *(const f16x8*)&msg_in[(size_t)n4 * HP + kk];
        av[5] = *(const f16x8*)&msg_in[(size_t)n5 * HP + kk];
      }
    }
  };

  auto issueB = [&](int ks, f16x8& pw0, f16x8& pw1, f16x8& pw2) {
    const int kw = ks * BK;
    pw0 = *(const f16x8*)&Wp[(size_t)br0 * KP_C + kw + bc0];
    pw1 = *(const f16x8*)&Wp[(size_t)br1 * KP_C + kw + bc1];
    if (b2ok) pw2 = *(const f16x8*)&Wp[(size_t)br2 * KP_C + kw + bc2];
  };

  auto write_lds = [&](int buf, int ks, f16x8& ax, f16x8& ay, f16x8 (&av)[6],
                       f16x8& pw0, f16x8& pw1, f16x8& pw2) {
    f16x8 pa = ax;
    if constexpr (MODE == 1) {
      if (ks >= ASTEPS) pa = ax - ay;
    }
    if constexpr (MODE == 2) {
      if (ks >= ASTEPS) pa = ((av[0] + av[1]) + (av[2] + av[3])) + (av[4] + av[5]);
    }
    *(f16x8*)&As[buf][arow][ac] = pa;
    *(f16x8*)&Bs[buf][br0][bc0] = pw0;
    *(f16x8*)&Bs[buf][br1][bc1] = pw1;
    if (b2ok) *(f16x8*)&Bs[buf][br2][bc2] = pw2;
  };

  const int row16 = lane & 15, kh = (lane >> 4) * 8;

  auto compute = [&](int buf) {
    f16x8 af[4], bfr[5];
#pragma unroll
    for (int m = 0; m < 4; ++m)
      af[m] = *(const f16x8*)&As[buf][wr * 64 + m * 16 + row16][kh];
#pragma unroll
    for (int n = 0; n < 5; ++n)
      bfr[n] = *(const f16x8*)&Bs[buf][wc * 80 + n * 16 + row16][kh];
#pragma unroll
    for (int m = 0; m < 4; ++m)
#pragma unroll
      for (int n = 0; n < 5; ++n)
        acc[m][n] = __builtin_amdgcn_mfma_f32_16x16x32_f16(af[m], bfr[n], acc[m][n], 0, 0, 0);
  };

  // prologue: even-ks state in the A/pwA sets, odd-ks state in B/pwB sets
  issueA(0, axA, ayA, avA); issueB(0, pwA0, pwA1, pwA2);
  write_lds(0, 0, axA, ayA, avA, pwA0, pwA1, pwA2);
  issueA(1, axB, ayB, avB); issueB(1, pwB0, pwB1, pwB2);
  __syncthreads();

  for (int ks = 0; ks < KSTEPS; ks += 2) {
    // ---- even step: computes global step ks in buf0 ----
    if (ks + 2 < KSTEPS) {                       // 2-deep issue of A and B
      issueA(ks + 2, axA, ayA, avA);
      issueB(ks + 2, pwA0, pwA1, pwA2);
    }
    compute(0);
    if (ks + 1 < KSTEPS)
      write_lds(1, ks + 1, axB, ayB, avB, pwB0, pwB1, pwB2);
    __syncthreads();
    // ---- odd step: computes global step ks+1 in buf1 ----
    if (ks + 1 < KSTEPS) {
      if (ks + 3 < KSTEPS) {
        issueA(ks + 3, axB, ayB, avB);
        issueB(ks + 3, pwB0, pwB1, pwB2);
      }
      compute(1);
      if (ks + 2 < KSTEPS)
        write_lds(0, ks + 2, axA, ayA, avA, pwA0, pwA1, pwA2);
      __syncthreads();
    }
  }

  // epilogue: C/D layout col = lane&15, row = (lane>>4)*4 + j  [m89]
  const int rquad = (lane >> 4) * 4;
#pragma unroll
  for (int m = 0; m < 4; ++m) {
#pragma unroll
    for (int n = 0; n < 5; ++n) {
      const int col = wc * 80 + n * 16 + row16;   // < 320 always
#pragma unroll
      for (int j = 0; j < 4; ++j) {
        const int row = mb * BM + wr * 64 + m * 16 + rquad + j;
        float v = acc[m][n][j];
        if constexpr (MODE == 2) {
          if (row < M && col < H)
            out_f32[(size_t)row * H + col] = fmaxf(v + b_o[col], 0.0f);
        } else {
          if (row < M)
            out_msg[(size_t)row * HP + col] = (f16)fmaxf(v, 0.0f);
        }
      }
    }
  }
}

extern "C" void kernel_launch(void* const* d_in, const int* in_sizes, int n_in,
                              void* d_out, int out_size, void* d_ws, size_t ws_size,
                              hipStream_t stream) {
  const float* f_atoms = (const float*)d_in[0];
  const float* f_bonds = (const float*)d_in[1];
  const int*   a2b     = (const int*)d_in[2];
  const int*   b2a     = (const int*)d_in[3];
  const int*   b2revb  = (const int*)d_in[4];
  const float* W_i     = (const float*)d_in[5];
  const float* W_h     = (const float*)d_in[6];
  const float* W_o     = (const float*)d_in[7];
  const float* b_o     = (const float*)d_in[8];
  float* out = (float*)d_out;

  char* ws = (char*)d_ws;
  size_t off = 0;
  f16* msgA = (f16*)(ws + off); off += (size_t)NB * HP * 2;   // 128.0 MB
  f16* msgB = (f16*)(ws + off); off += (size_t)NB * HP * 2;   // 128.0 MB
  f16* amsg = (f16*)(ws + off); off += (size_t)NA * HP * 2;   //  64.0 MB
  f16* fb16 = (f16*)(ws + off); off += (size_t)NB * AFP * 2;  //  64.0 MB
  f16* fa16 = (f16*)(ws + off); off += (size_t)NA * AFP * 2;  //  32.0 MB
  f16* W1P  = (f16*)(ws + off); off += (size_t)NP * KP_C * 2;
  f16* WoP  = (f16*)(ws + off); off += (size_t)NP * KP_C * 2;
  if (off > ws_size) return;  // total ~416.6 MB (known-good budget)

  prep_w1<<<(NP * KP_C + 255) / 256, 256, 0, stream>>>(W_i, W_h, W1P);
  prep_wo<<<(NP * KP_C + 255) / 256, 256, 0, stream>>>(W_o, WoP);
  conv_pad_f16<<<(NB * (AFP / 8) + 255) / 256, 256, 0, stream>>>(f_bonds, fb16, NB, BF);
  conv_pad_f16<<<(NA * (AFP / 8) + 255) / 256, 256, 0, stream>>>(f_atoms, fa16, NA, AF);

  const int gB = (NB + BM - 1) / BM;   // 1563
  const int gA = (NA + BM - 1) / BM;   // 782
  dim3 gS((NA * (HP / 8) + 255) / 256);

  // msgA = relu(fb16 @ W_i)
  gemm_kernel<0><<<gB, NTH, 0, stream>>>(fb16, nullptr, nullptr,
                                         nullptr, nullptr, nullptr, W1P, nullptr,
                                         msgA, nullptr);
  // iteration 1: msgB = relu(inp + (amsg[b2a]-msgA[b2revb]) @ W_h)  [K=480 fused]
  gather_sum_kernel<<<gS, 256, 0, stream>>>(msgA, a2b, amsg);
  gemm_kernel<1><<<gB, NTH, 0, stream>>>(fb16, amsg, msgA,
                                         b2a, b2revb, nullptr, W1P, nullptr,
                                         msgB, nullptr);
  // iteration 2
  gather_sum_kernel<<<gS, 256, 0, stream>>>(msgB, a2b, amsg);
  gemm_kernel<1><<<gB, NTH, 0, stream>>>(fb16, amsg, msgB,
                                         b2a, b2revb, nullptr, W1P, nullptr,
                                         msgA, nullptr);
  // readout: final gather fused into gemm2's A-load (no standalone gather#3)
  gemm_kernel<2><<<gA, NTH, 0, stream>>>(fa16, nullptr, msgA,
                                         nullptr, nullptr, a2b, WoP, b_o,
                                         nullptr, out);
}

// Round 19
// 620.768 us; speedup vs baseline: 1.1445x; 1.1445x over previous
//
#include <hip/hip_runtime.h>
#include <hip/hip_fp16.h>

#define NA 100000
#define NB 200000
#define MAXNB 6
#define AF 133
#define BF 147
#define H 300
#define HP 320     // fp16 row width for amsg / final msg (640B)
#define HP8 320    // fp8 row width for early msg (320B)
#define AFP 160    // padded fp16 row width for f_bonds/f_atoms
#define NP 320     // weight N padding = BN
#define KP_C 480   // uniform K padding: [W_i(160); W_h(320)] / [atoms(160); amsg(320)]
#define BM 128
#define BN 320
#define BK 32
#define NTH 512
#define LDK 40     // LDS row stride (32 + 8 pad)

typedef _Float16 f16;
typedef __attribute__((ext_vector_type(8))) _Float16 f16x8;
typedef __attribute__((ext_vector_type(4))) float f32x4;
typedef __attribute__((ext_vector_type(2))) float f32x2;
typedef __attribute__((ext_vector_type(8))) float f32x8;
typedef __attribute__((ext_vector_type(2))) unsigned int u32x2;

// ---- fp8 e4m3 (OCP on gfx950) helpers -------------------------------------
__device__ inline f32x8 fp8x8_to_f32x8(u32x2 v) {
  f32x2 a0 = __builtin_amdgcn_cvt_pk_f32_fp8(v.x, false);
  f32x2 a1 = __builtin_amdgcn_cvt_pk_f32_fp8(v.x, true);
  f32x2 a2 = __builtin_amdgcn_cvt_pk_f32_fp8(v.y, false);
  f32x2 a3 = __builtin_amdgcn_cvt_pk_f32_fp8(v.y, true);
  f32x8 r;
  r[0] = a0[0]; r[1] = a0[1]; r[2] = a1[0]; r[3] = a1[1];
  r[4] = a2[0]; r[5] = a2[1]; r[6] = a3[0]; r[7] = a3[1];
  return r;
}
__device__ inline unsigned char f32_to_fp8_1(float v) {
  return (unsigned char)(__builtin_amdgcn_cvt_pk_fp8_f32(v, v, 0, false) & 0xff);
}

// ---- fp32 [M][Ks] -> fp16 [M][160] zero-padded ----------------------------
__global__ void conv_pad_f16(const float* __restrict__ src, f16* __restrict__ dst,
                             int M, int Ks) {
  int idx = blockIdx.x * blockDim.x + threadIdx.x;
  if (idx >= M * (AFP / 8)) return;
  int r = idx / (AFP / 8);
  int c = (idx - r * (AFP / 8)) * 8;
  f16x8 o;
#pragma unroll
  for (int j = 0; j < 8; ++j) {
    int k = c + j;
    o[j] = (k < Ks) ? (f16)src[(size_t)r * Ks + k] : (f16)0.0f;
  }
  *(f16x8*)&dst[(size_t)r * AFP + c] = o;
}

// ---- stacked [W_i; W_h] -> [n][k] fp16, stride KP_C ------------------------
__global__ void prep_w1(const float* __restrict__ Wi, const float* __restrict__ Wh,
                        f16* __restrict__ dst) {
  int idx = blockIdx.x * blockDim.x + threadIdx.x;
  if (idx >= NP * KP_C) return;
  int n = idx / KP_C, k = idx - n * KP_C;
  float v = 0.0f;
  if (n < H) {
    if (k < BF) v = Wi[(size_t)k * H + n];
    else if (k >= AFP && k < AFP + H) v = Wh[(size_t)(k - AFP) * H + n];
  }
  dst[idx] = (f16)v;
}

// ---- W_o remapped for [f_atoms(133->160 pad), amsg(300->320 pad)] ----------
__global__ void prep_wo(const float* __restrict__ src, f16* __restrict__ dst) {
  int idx = blockIdx.x * blockDim.x + threadIdx.x;
  if (idx >= NP * KP_C) return;
  int n = idx / KP_C, k = idx - n * KP_C;
  int ks = -1;
  if (k < AF) ks = k;
  else if (k >= AFP && k < AFP + H) ks = AF + (k - AFP);
  float v = (n < H && ks >= 0) ? src[(size_t)ks * H + n] : 0.0f;
  dst[idx] = (f16)v;
}

// ---- a_msg[a][:] = sum_t msg[a2b[a][t]][:]  (fp8 in, fp16 out — NO requant) -
__global__ void gather_sum_kernel(const unsigned char* __restrict__ msg,
                                  const int* __restrict__ a2b,
                                  f16* __restrict__ amsg) {
  int idx = blockIdx.x * blockDim.x + threadIdx.x;
  if (idx >= NA * (HP / 8)) return;
  int a = idx / (HP / 8);
  int c = (idx - a * (HP / 8)) * 8;
  const int* nbr = &a2b[(size_t)a * MAXNB];
  float acc[8] = {0.f, 0.f, 0.f, 0.f, 0.f, 0.f, 0.f, 0.f};
#pragma unroll
  for (int t = 0; t < MAXNB; ++t) {
    u32x2 v = *(const u32x2*)&msg[(size_t)nbr[t] * HP8 + c];
    f32x8 f = fp8x8_to_f32x8(v);
#pragma unroll
    for (int j = 0; j < 8; ++j) acc[j] += f[j];
  }
  f16x8 o;
#pragma unroll
  for (int j = 0; j < 8; ++j) o[j] = (f16)acc[j];
  *(f16x8*)&amsg[(size_t)a * HP + c] = o;
}

// ---- unified GEMM: 128x320 tile, 8 waves (2x4), BK=32, dbuf LDS -----------
// ONE barrier per k-step; A 2-deep (issued at iteration top), B 1-deep.
// MODE 0: msg8 = relu(fb16 @ W_i)                               (K=160, fp8 out)
// MODE 1: msg' = relu([fb16[m], amsg16[b2a]-msg8[b2revb]] @ [W_i;W_h]) (K=480)
//         OUT8 ? fp8 out (iteration 1) : fp16 out (final iteration)
// MODE 2: out = relu([fa16, sum_t msg16[a2b[m][t]]] @ W_o + b_o) (K=480, fused)
template <int MODE, bool OUT8>
__global__ __launch_bounds__(NTH)
void gemm_kernel(const f16* __restrict__ Afp,     // fb16 (MODE 0/1) / fa16 (MODE 2)
                 const f16* __restrict__ amsg,    // MODE1: gathered sums (fp16)
                 const unsigned char* __restrict__ msg8_in,  // MODE1: prev msg (fp8)
                 const f16* __restrict__ msg16_in,           // MODE2: final msg (fp16)
                 const int* __restrict__ b2a,
                 const int* __restrict__ b2revb,
                 const int* __restrict__ a2b,     // MODE2 only
                 const f16* __restrict__ Wp,      // [NP][KP_C]
                 const float* __restrict__ b_o,
                 unsigned char* __restrict__ out_msg8,
                 f16* __restrict__ out_msg16,
                 float* __restrict__ out_f32) {
  constexpr int KSTEPS = (MODE == 0) ? 5 : 15;
  constexpr int ASTEPS = 5;                // k-steps sourced from Afp
  constexpr int M = (MODE == 2) ? NA : NB;

  __shared__ f16 As[2][BM][LDK];
  __shared__ f16 Bs[2][BN][LDK];

  const int mb = blockIdx.x;
  const int tid = threadIdx.x;
  const int lane = tid & 63, wid = tid >> 6;
  const int wr = wid >> 2, wc = wid & 3;   // 2 x 4 wave grid

  f32x4 acc[4][5] = {};

  // A staging: 512 8-elem chunks == NTH; thread -> (tid>>2, (tid&3)*8)
  const int arow = tid >> 2;
  const int ac = (tid & 3) * 8;
  const int m_g = mb * BM + arow;
  const int mrow = (m_g < M) ? m_g : 0;  // clamp: OOB rows masked in epilogue

  // B staging: 1280 chunks over 512 threads (3rd chunk partial, tid<256)
  const int bidx2 = tid + 2 * NTH;
  const int br0 = tid >> 2,            bc0 = (tid & 3) * 8;
  const int br1 = (tid + NTH) >> 2,    bc1 = ((tid + NTH) & 3) * 8;
  const int br2 = bidx2 >> 2,          bc2 = (bidx2 & 3) * 8;
  const bool b2ok = bidx2 < BN * 4;

  int ra = 0, rb = 0;
  int n0 = 0, n1 = 0, n2 = 0, n3 = 0, n4 = 0, n5 = 0;
  if constexpr (MODE == 1) { ra = b2a[mrow]; rb = b2revb[mrow]; }
  if constexpr (MODE == 2) {
    const int* p = &a2b[(size_t)mrow * MAXNB];
    n0 = p[0]; n1 = p[1]; n2 = p[2]; n3 = p[3]; n4 = p[4]; n5 = p[5];
  }

  // two alternating A-staging sets (static names, rule #20); one B set
  f16x8 axA, avA[6];
  u32x2 ayA8;
  f16x8 axB, avB[6];
  u32x2 ayB8;
  f16x8 pw0, pw1, pw2;

  auto issueA = [&](int ks, f16x8& ax, u32x2& ay8, f16x8 (&av)[6]) {
    const int kb = ks * BK + ac;
    if constexpr (MODE == 0) {
      ax = *(const f16x8*)&Afp[(size_t)mrow * AFP + kb];
    } else if constexpr (MODE == 1) {
      if (ks < ASTEPS) {
        ax = *(const f16x8*)&Afp[(size_t)mrow * AFP + kb];
      } else {
        const int kk = kb - AFP;
        ax = *(const f16x8*)&amsg[(size_t)ra * HP + kk];            // fp16
        ay8 = *(const u32x2*)&msg8_in[(size_t)rb * HP8 + kk];       // fp8
      }
    } else {
      if (ks < ASTEPS) {
        ax = *(const f16x8*)&Afp[(size_t)mrow * AFP + kb];
      } else {
        const int kk = kb - AFP;
        av[0] = *(const f16x8*)&msg16_in[(size_t)n0 * HP + kk];
        av[1] = *(const f16x8*)&msg16_in[(size_t)n1 * HP + kk];
        av[2] = *(const f16x8*)&msg16_in[(size_t)n2 * HP + kk];
        av[3] = *(const f16x8*)&msg16_in[(size_t)n3 * HP + kk];
        av[4] = *(const f16x8*)&msg16_in[(size_t)n4 * HP + kk];
        av[5] = *(const f16x8*)&msg16_in[(size_t)n5 * HP + kk];
      }
    }
  };

  auto issueB = [&](int ks) {
    const int kw = ks * BK;
    pw0 = *(const f16x8*)&Wp[(size_t)br0 * KP_C + kw + bc0];
    pw1 = *(const f16x8*)&Wp[(size_t)br1 * KP_C + kw + bc1];
    if (b2ok) pw2 = *(const f16x8*)&Wp[(size_t)br2 * KP_C + kw + bc2];
  };

  auto write_lds = [&](int buf, int ks, f16x8& ax, u32x2& ay8, f16x8 (&av)[6]) {
    f16x8 pa;
    if constexpr (MODE == 0) {
      pa = ax;
    } else if constexpr (MODE == 1) {
      if (ks < ASTEPS) {
        pa = ax;
      } else {
        f32x8 ya = fp8x8_to_f32x8(ay8);
#pragma unroll
        for (int j = 0; j < 8; ++j) pa[j] = (f16)((float)ax[j] - ya[j]);
      }
    } else {
      if (ks < ASTEPS) {
        pa = ax;
      } else {
        pa = ((av[0] + av[1]) + (av[2] + av[3])) + (av[4] + av[5]);
      }
    }
    *(f16x8*)&As[buf][arow][ac] = pa;
    *(f16x8*)&Bs[buf][br0][bc0] = pw0;
    *(f16x8*)&Bs[buf][br1][bc1] = pw1;
    if (b2ok) *(f16x8*)&Bs[buf][br2][bc2] = pw2;
  };

  const int row16 = lane & 15, kh = (lane >> 4) * 8;

  auto compute = [&](int buf) {
    f16x8 af[4], bfr[5];
#pragma unroll
    for (int m = 0; m < 4; ++m)
      af[m] = *(const f16x8*)&As[buf][wr * 64 + m * 16 + row16][kh];
#pragma unroll
    for (int n = 0; n < 5; ++n)
      bfr[n] = *(const f16x8*)&Bs[buf][wc * 80 + n * 16 + row16][kh];
#pragma unroll
    for (int m = 0; m < 4; ++m)
#pragma unroll
      for (int n = 0; n < 5; ++n)
        acc[m][n] = __builtin_amdgcn_mfma_f32_16x16x32_f16(af[m], bfr[n], acc[m][n], 0, 0, 0);
  };

  // prologue: even-ks state in A-set, odd-ks state in B-set
  issueA(0, axA, ayA8, avA); issueB(0);
  write_lds(0, 0, axA, ayA8, avA);
  issueA(1, axB, ayB8, avB); issueB(1);
  __syncthreads();

  for (int ks = 0; ks < KSTEPS; ks += 2) {
    // ---- even step: computes global step ks in buf0 ----
    if (ks + 2 < KSTEPS) issueA(ks + 2, axA, ayA8, avA);   // 2-deep issue
    compute(0);
    if (ks + 1 < KSTEPS) write_lds(1, ks + 1, axB, ayB8, avB);
    if (ks + 2 < KSTEPS) issueB(ks + 2);
    __syncthreads();
    // ---- odd step: computes global step ks+1 in buf1 ----
    if (ks + 1 < KSTEPS) {
      if (ks + 3 < KSTEPS) issueA(ks + 3, axB, ayB8, avB); // 2-deep issue
      compute(1);
      if (ks + 2 < KSTEPS) write_lds(0, ks + 2, axA, ayA8, avA);
      if (ks + 3 < KSTEPS) issueB(ks + 3);
      __syncthreads();
    }
  }

  // epilogue: C/D layout col = lane&15, row = (lane>>4)*4 + j  [m89]
  const int rquad = (lane >> 4) * 4;
#pragma unroll
  for (int m = 0; m < 4; ++m) {
#pragma unroll
    for (int n = 0; n < 5; ++n) {
      const int col = wc * 80 + n * 16 + row16;   // < 320 always
#pragma unroll
      for (int j = 0; j < 4; ++j) {
        const int row = mb * BM + wr * 64 + m * 16 + rquad + j;
        float v = acc[m][n][j];
        if constexpr (MODE == 2) {
          if (row < M && col < H)
            out_f32[(size_t)row * H + col] = fmaxf(v + b_o[col], 0.0f);
        } else if constexpr (OUT8) {
          if (row < M)
            out_msg8[(size_t)row * HP8 + col] = f32_to_fp8_1(fmaxf(v, 0.0f));
        } else {
          if (row < M)
            out_msg16[(size_t)row * HP + col] = (f16)fmaxf(v, 0.0f);
        }
      }
    }
  }
}

extern "C" void kernel_launch(void* const* d_in, const int* in_sizes, int n_in,
                              void* d_out, int out_size, void* d_ws, size_t ws_size,
                              hipStream_t stream) {
  const float* f_atoms = (const float*)d_in[0];
  const float* f_bonds = (const float*)d_in[1];
  const int*   a2b     = (const int*)d_in[2];
  const int*   b2a     = (const int*)d_in[3];
  const int*   b2revb  = (const int*)d_in[4];
  const float* W_i     = (const float*)d_in[5];
  const float* W_h     = (const float*)d_in[6];
  const float* W_o     = (const float*)d_in[7];
  const float* b_o     = (const float*)d_in[8];
  float* out = (float*)d_out;

  char* ws = (char*)d_ws;
  size_t off = 0;
  unsigned char* msgA8 = (unsigned char*)(ws + off); off += (size_t)NB * HP8; // 64.0 MB
  unsigned char* msgB8 = (unsigned char*)(ws + off); off += (size_t)NB * HP8; // 64.0 MB
  f16* msgF = (f16*)(ws + off); off += (size_t)NB * HP * 2;                   // 128.0 MB
  f16* amsg = (f16*)(ws + off); off += (size_t)NA * HP * 2;                   //  64.0 MB
  f16* fb16 = (f16*)(ws + off); off += (size_t)NB * AFP * 2;                  //  64.0 MB
  f16* fa16 = (f16*)(ws + off); off += (size_t)NA * AFP * 2;                  //  32.0 MB
  f16* W1P  = (f16*)(ws + off); off += (size_t)NP * KP_C * 2;
  f16* WoP  = (f16*)(ws + off); off += (size_t)NP * KP_C * 2;
  if (off > ws_size) return;  // total ~416.6 MB (known-good budget)

  prep_w1<<<(NP * KP_C + 255) / 256, 256, 0, stream>>>(W_i, W_h, W1P);
  prep_wo<<<(NP * KP_C + 255) / 256, 256, 0, stream>>>(W_o, WoP);
  conv_pad_f16<<<(NB * (AFP / 8) + 255) / 256, 256, 0, stream>>>(f_bonds, fb16, NB, BF);
  conv_pad_f16<<<(NA * (AFP / 8) + 255) / 256, 256, 0, stream>>>(f_atoms, fa16, NA, AF);

  const int gB = (NB + BM - 1) / BM;   // 1563
  const int gA = (NA + BM - 1) / BM;   // 782
  dim3 gS((NA * (HP / 8) + 255) / 256);

  // msgA8 = relu(fb16 @ W_i)   [fp8 out — quant event 1]
  gemm_kernel<0, true><<<gB, NTH, 0, stream>>>(fb16, nullptr, nullptr, nullptr,
                                               nullptr, nullptr, nullptr, W1P, nullptr,
                                               msgA8, nullptr, nullptr);
  // iteration 1: msgB8 = relu([fb16, amsg-msgA8[rb]] @ W1)  [fp8 out — quant event 2]
  gather_sum_kernel<<<gS, 256, 0, stream>>>(msgA8, a2b, amsg);
  gemm_kernel<1, true><<<gB, NTH, 0, stream>>>(fb16, amsg, msgA8, nullptr,
                                               b2a, b2revb, nullptr, W1P, nullptr,
                                               msgB8, nullptr, nullptr);
  // iteration 2: msgF = relu([fb16, amsg-msgB8[rb]] @ W1)   [fp16 out — full precision]
  gather_sum_kernel<<<gS, 256, 0, stream>>>(msgB8, a2b, amsg);
  gemm_kernel<1, false><<<gB, NTH, 0, stream>>>(fb16, amsg, msgB8, nullptr,
                                                b2a, b2revb, nullptr, W1P, nullptr,
                                                nullptr, msgF, nullptr);
  // readout: final gather (fp16) fused into gemm2's A-load
  gemm_kernel<2, false><<<gA, NTH, 0, stream>>>(fa16, nullptr, nullptr, msgF,
                                                nullptr, nullptr, a2b, WoP, b_o,
                                                nullptr, nullptr, out);
}